// Round 9
// baseline (652.146 us; speedup 1.0000x reference)
//
#include <hip/hip_runtime.h>
#include <hip/hip_bf16.h>
#include <stdint.h>

// Problem constants
#define KK   8192
#define NN   16384      // B*H*W tokens
#define CCH  256        // channels

#define QE_SIZE  4194304            // NN*CCH floats
#define LOSS_OFF QE_SIZE
#define IDX_OFF  (QE_SIZE + 1)

// ws layout (bytes) — ~10.4 MB
#define B2_OFF     0ULL                              // ushort B2[8192][512] = [hi|lo]
#define HN_OFF     (B2_OFF + 8192ULL*512*2)          // float hn[8192]
#define P1D_OFF    (HN_OFF + 8192ULL*4)              // float pd1[8][16384]
#define P1I_OFF    (P1D_OFF + 8ULL*16384*4)          // int   pi1[8][16384]
#define P2D_OFF    (P1I_OFF + 8ULL*16384*4)          // float pd2[8][16384]
#define P2I_OFF    (P2D_OFF + 8ULL*16384*4)          // int   pi2[8][16384]

typedef __attribute__((ext_vector_type(8))) short   bf16x8;
typedef __attribute__((ext_vector_type(8))) unsigned short ushort8v;
typedef __attribute__((ext_vector_type(4))) float   f32x4;

__device__ __forceinline__ void gld16(const void* g, void* l) {
    __builtin_amdgcn_global_load_lds(
        (const __attribute__((address_space(1))) void*)g,
        (__attribute__((address_space(3))) void*)l, 16, 0, 0);
}

// round-to-nearest-even fp32 -> bf16 bits
__device__ __forceinline__ unsigned short bf16_rn(float v) {
    uint32_t u = __float_as_uint(v);
    return (unsigned short)((u + 0x7fffu + ((u >> 16) & 1u)) >> 16);
}

// merge other top-2 (t1,j1,t2,j2) into mine (s1,i1,s2,i2); higher score wins,
// ties -> smaller index (first-occurrence argmin semantics)
__device__ __forceinline__ void top2_merge(float& s1, int& i1, float& s2, int& i2,
                                           float t1, int j1, float t2, int j2) {
    if (t1 > s1 || (t1 == s1 && j1 < i1)) {
        float ns2; int ni2;
        if (s1 > t2 || (s1 == t2 && i1 < j2)) { ns2 = s1; ni2 = i1; }
        else                                   { ns2 = t2; ni2 = j2; }
        s1 = t1; i1 = j1; s2 = ns2; i2 = ni2;
    } else {
        if (t1 > s2 || (t1 == s2 && j1 < i2)) { s2 = t1; i2 = j1; }
    }
}

// ---------------------------------------------------------------------------
// Prep 1: split x -> A-FRAGMENT-MAJOR layout in d_out's qe region (16 MiB).
// For 16-token tile tb = n>>4, virtual k-step ks (0..15 over [hi|lo]),
// lane l: 8 bf16 of token tb*16+(l&15), channels ks*32 + (l>>4)*8.
// Frag addr (elements) = ((tb*16 + ks)*64 + l)*8.
// ---------------------------------------------------------------------------
__global__ __launch_bounds__(256) void split_x_kernel(const float* __restrict__ x,
                                                      unsigned short* __restrict__ A) {
    __shared__ float xt[256 * 64];      // [c][tok] 64 KB
    const int t = threadIdx.x;
    const int n0 = blockIdx.x * 64;
    const int b = n0 >> 10, hw0 = n0 & 1023;
    const int tok_l = t & 63, cg = t >> 6;
    const float* xb = x + ((size_t)b << 18) + hw0 + tok_l;
    #pragma unroll 8
    for (int i = 0; i < 64; ++i) {
        int c = cg * 64 + i;
        xt[c * 64 + tok_l] = xb[(size_t)c << 10];
    }
    __syncthreads();
    const int tokq = t >> 5;            // 8 tokens per pass
    const int c8 = (t & 31) * 8;
    const int ksh = c8 >> 5;            // hi ks
    const int lq  = (c8 >> 3) & 3;      // quad within frag
    for (int p = 0; p < 8; ++p) {
        int tk = p * 8 + tokq;
        unsigned short hi[8], lo[8];
        #pragma unroll
        for (int u = 0; u < 8; ++u) {
            float v = xt[(c8 + u) * 64 + tk];
            unsigned short h = bf16_rn(v);
            float fh = __uint_as_float(((uint32_t)h) << 16);
            lo[u] = bf16_rn(v - fh);
            hi[u] = h;
        }
        const int n  = n0 + tk;
        const int tb = n >> 4;
        const int l  = (tk & 15) + 16 * lq;
        *(ushort8v*)(A + ((size_t)((tb * 16 + ksh)     * 64) + l) * 8) = *(ushort8v*)hi;
        *(ushort8v*)(A + ((size_t)((tb * 16 + 8 + ksh) * 64) + l) * 8) = *(ushort8v*)lo;
    }
}

// ---------------------------------------------------------------------------
// Prep 2: split codebook [8192][256] -> B2[k][512] = [hi | lo] (bf16) and
// hn[k] = 0.5*||e_k||^2 (fp32 exact). 32 threads per code row.
// ---------------------------------------------------------------------------
__global__ __launch_bounds__(256) void split_cb_kernel(const float* __restrict__ cb,
                                                       unsigned short* __restrict__ B2,
                                                       float* __restrict__ hn) {
    const int t = threadIdx.x;
    const int code = blockIdx.x * 8 + (t >> 5);
    const int c8 = (t & 31) * 8;
    const float* cr = cb + (size_t)code * CCH + c8;
    float s = 0.f;
    unsigned short hi[8], lo[8];
    #pragma unroll
    for (int u = 0; u < 8; ++u) {
        float v = cr[u];
        s += v * v;
        unsigned short h = bf16_rn(v);
        float fh = __uint_as_float(((uint32_t)h) << 16);
        lo[u] = bf16_rn(v - fh);
        hi[u] = h;
    }
    unsigned short* Br = B2 + (size_t)code * 512;
    *(ushort8v*)(Br + c8)       = *(ushort8v*)hi;
    *(ushort8v*)(Br + 256 + c8) = *(ushort8v*)lo;
    #pragma unroll
    for (int off = 16; off; off >>= 1) s += __shfl_xor(s, off);
    if ((t & 31) == 0) hn[code] = 0.5f * s;
}

// ---------------------------------------------------------------------------
// Main: bf16 MFMA GEMM, fused TOP-2 of (dot - 0.5||e||^2).
// Block = 128 tokens x 1024 codes (one EIGHTH); grid 1024 -> 4 blocks/CU.
// Wave owns 32 tokens with A resident in 128 regs (2 tiles x 16 frags).
// N-tile = 64 codes: acc[2][4]=32 regs, bfr[4]=16 -> ~120 VGPR, no spill at
// 4 blocks/CU (cap 128). Per N-tile: 8 B-slab stages (4 hi + 4 lo, 8 KB)
// double-buffered; prefetch issued after the barrier, flies under the MFMA.
// ---------------------------------------------------------------------------
__global__ __launch_bounds__(256, 4) void vq_gemm_kernel(const unsigned short* __restrict__ A,
                                                         const unsigned short* __restrict__ B2,
                                                         const float* __restrict__ hn,
                                                         float* __restrict__ pd1,
                                                         int*   __restrict__ pi1,
                                                         float* __restrict__ pd2,
                                                         int*   __restrict__ pi2) {
    __shared__ unsigned short Bsm[2][64 * 64];    // 2 x 8 KB ping-pong

    const int t = threadIdx.x;
    const int lane = t & 63, wave = t >> 6;
    const int l15 = lane & 15, quad = lane >> 4;

    const int mblk = blockIdx.x & 127;        // 128 M-blocks of 128 tokens
    const int nq   = blockIdx.x >> 7;         // 8 code eighths
    const int codeQ = nq * 1024;

    // A fragments: 32 coalesced dwordx4 loads, resident for the whole kernel
    bf16x8 af[2][16];
    #pragma unroll
    for (int i = 0; i < 2; ++i) {
        const int tb = mblk * 8 + wave * 2 + i;   // 16-token tile id
        const unsigned short* Abase = A + ((size_t)(tb * 16) * 64 + lane) * 8;
        #pragma unroll
        for (int ks = 0; ks < 16; ++ks)
            af[i][ks] = *(const bf16x8*)(Abase + (size_t)ks * 64 * 8);
    }

    // B staging geometry (global_load_lds: wave-uniform base + lane*16)
    const int srow = wave * 8 + (lane >> 3);          // + it*32
    const int sch  = (lane & 7) ^ (srow & 7);         // swizzled source chunk

    // stage GN (0..127): ntn = GN>>3 (64-code tile), stn = GN&7
    // stn 0-3: B hi slabs (ch 0/64/128/192); stn 4-7: B lo slabs
#define STAGE_LOAD(GN)                                                         \
    do {                                                                       \
        const int ntn = (GN) >> 3, stn = (GN) & 7;                             \
        const int bkt = (stn & 3) * 64 + (stn >> 2) * 256;                     \
        const size_t bOff = (size_t)(codeQ + ntn * 64 + srow) * 512            \
                            + sch * 8 + bkt;                                   \
        char* dst = (char*)Bsm[(GN) & 1] + wave * 1024;                        \
        _Pragma("unroll")                                                      \
        for (int it = 0; it < 2; ++it)                                         \
            gld16(B2 + bOff + (size_t)it * (32 * 512), dst + it * 4096);       \
    } while (0)

    float rs1[2][4], rs2[2][4];
    int   ri1[2][4], ri2[2][4];
    #pragma unroll
    for (int i = 0; i < 2; ++i)
        #pragma unroll
        for (int r = 0; r < 4; ++r) {
            rs1[i][r] = -1e30f; ri1[i][r] = 0x7fffffff;
            rs2[i][r] = -1e30f; ri2[i][r] = 0x7fffffff;
        }

    STAGE_LOAD(0);                                     // prologue prefetch
    int g = 0;

    #pragma unroll 1
    for (int nt = 0; nt < 16; ++nt) {
        const int code0 = codeQ + nt * 64;
        f32x4 acc[2][4];
        #pragma unroll
        for (int i = 0; i < 2; ++i)
            #pragma unroll
            for (int j = 0; j < 4; ++j) {
                f32x4 z = {0.f, 0.f, 0.f, 0.f};
                acc[i][j] = z;
            }

        #pragma unroll
        for (int st = 0; st < 8; ++st) {
            __syncthreads();                           // stage g drained; prev reads done
            if (g + 1 < 128) STAGE_LOAD(g + 1);        // prefetch under this stage's MFMA
            const char* bs = (const char*)Bsm[g & 1];

            #pragma unroll
            for (int ks2 = 0; ks2 < 2; ++ks2) {
                bf16x8 bfr[4];
                #pragma unroll
                for (int j = 0; j < 4; ++j) {
                    const int rowB = j * 16 + l15;
                    const int cbk = ((quad ^ (rowB & 7)) ^ (ks2 << 2)) * 16;
                    bfr[j] = *(const bf16x8*)(bs + rowB * 128 + cbk);
                }
                if (st < 4) {
                    const int ka = st * 2 + ks2;       // A hi + A lo vs B hi
                    #pragma unroll
                    for (int i = 0; i < 2; ++i) {
                        #pragma unroll
                        for (int j = 0; j < 4; ++j)
                            acc[i][j] = __builtin_amdgcn_mfma_f32_16x16x32_bf16(
                                af[i][ka], bfr[j], acc[i][j], 0, 0, 0);
                        #pragma unroll
                        for (int j = 0; j < 4; ++j)
                            acc[i][j] = __builtin_amdgcn_mfma_f32_16x16x32_bf16(
                                af[i][8 + ka], bfr[j], acc[i][j], 0, 0, 0);
                    }
                } else {
                    const int ka = (st - 4) * 2 + ks2; // A hi vs B lo
                    #pragma unroll
                    for (int i = 0; i < 2; ++i)
                        #pragma unroll
                        for (int j = 0; j < 4; ++j)
                            acc[i][j] = __builtin_amdgcn_mfma_f32_16x16x32_bf16(
                                af[i][ka], bfr[j], acc[i][j], 0, 0, 0);
                }
            }
            ++g;
        }

        // epilogue: top-2 of s = dot - 0.5||e||^2 (strict >, codes ascend)
        #pragma unroll
        for (int j = 0; j < 4; ++j) {
            const int cg = code0 + j * 16 + l15;
            const float h = hn[cg];
            #pragma unroll
            for (int i = 0; i < 2; ++i)
                #pragma unroll
                for (int r = 0; r < 4; ++r) {
                    const float s = acc[i][j][r] - h;
                    if (s > rs1[i][r]) {
                        rs2[i][r] = rs1[i][r]; ri2[i][r] = ri1[i][r];
                        rs1[i][r] = s;         ri1[i][r] = cg;
                    } else if (s > rs2[i][r]) {
                        rs2[i][r] = s; ri2[i][r] = cg;
                    }
                }
        }
    }
#undef STAGE_LOAD

    // top-2 butterfly across the 16-lane col groups (same tokens)
    #pragma unroll
    for (int off = 1; off < 16; off <<= 1) {
        #pragma unroll
        for (int i = 0; i < 2; ++i)
            #pragma unroll
            for (int r = 0; r < 4; ++r) {
                const float t1 = __shfl_xor(rs1[i][r], off);
                const int   j1 = __shfl_xor(ri1[i][r], off);
                const float t2 = __shfl_xor(rs2[i][r], off);
                const int   j2 = __shfl_xor(ri2[i][r], off);
                top2_merge(rs1[i][r], ri1[i][r], rs2[i][r], ri2[i][r],
                           t1, j1, t2, j2);
            }
    }

    // l15==0 lanes hold finals for tokens mblk*128 + wave*32 + i*16 + quad*4 + r
    if (l15 == 0) {
        #pragma unroll
        for (int i = 0; i < 2; ++i)
            #pragma unroll
            for (int r = 0; r < 4; ++r) {
                const int tok = mblk * 128 + wave * 32 + i * 16 + quad * 4 + r;
                const int gi = nq * NN + tok;
                pd1[gi] = rs1[i][r]; pi1[gi] = ri1[i][r];
                pd2[gi] = rs2[i][r]; pi2[gi] = ri2[i][r];
            }
    }
}

// ---------------------------------------------------------------------------
// Finalize (fused, coalesced): block = 64 tokens.
//  1) stage x[64 tokens][256 ch] into LDS via coalesced 256 B row reads
//  2) merge 8 quarters' top-2 per token (1 thread/token)
//  3) fp64 rescore of both candidates (tokens on lanes; cb 4 B L2 scatters)
//  4) qe write (coalesced along tokens) + commit-loss reduction
// ---------------------------------------------------------------------------
__global__ __launch_bounds__(256) void finalize_kernel(const float* __restrict__ x,
                                                       const float* __restrict__ cb,
                                                       const float* __restrict__ pd1,
                                                       const int*   __restrict__ pi1,
                                                       const float* __restrict__ pd2,
                                                       const int*   __restrict__ pi2,
                                                       float* __restrict__ qe,
                                                       float* __restrict__ idx_f,
                                                       float* __restrict__ loss) {
    __shared__ float  xt[256 * 64];     // [c][tok] 64 KB
    __shared__ int    cand1[64], cand2[64], bestsm[64];
    __shared__ double dp1[4][64], dp2[4][64];
    __shared__ float  wsum[4];

    const int t = threadIdx.x;
    const int n0 = blockIdx.x * 64;
    const int b = n0 >> 10, hw0 = n0 & 1023;
    const int tok = t & 63, cq = t >> 6;

    // 1) stage x (coalesced: 64 consecutive floats per row)
    {
        const float* xb = x + ((size_t)b << 18) + hw0 + tok;
        #pragma unroll 8
        for (int i = 0; i < 64; ++i) {
            const int c = cq * 64 + i;
            xt[c * 64 + tok] = xb[(size_t)c << 10];
        }
    }

    // 2) merge 8 quarters (thread t < 64 handles token n0+t)
    if (t < 64) {
        float s1 = -1e30f, s2 = -1e30f; int i1 = 0, i2 = 1;
        #pragma unroll
        for (int q = 0; q < 8; ++q) {
            const int g = q * NN + n0 + t;
            top2_merge(s1, i1, s2, i2, pd1[g], pi1[g], pd2[g], pi2[g]);
        }
        cand1[t] = i1; cand2[t] = i2;
    }
    __syncthreads();

    // 3) fp64 rescore: thread (tok, cq) covers channels cq*64..+63
    {
        const int i1 = cand1[tok], i2 = cand2[tok];
        const float* c1 = cb + (size_t)i1 * CCH + cq * 64;
        const float* c2 = cb + (size_t)i2 * CCH + cq * 64;
        double d1 = 0.0, d2 = 0.0;
        #pragma unroll 8
        for (int u = 0; u < 64; ++u) {
            const double xv = (double)xt[(cq * 64 + u) * 64 + tok];
            const double e1 = (double)c1[u];
            const double e2 = (double)c2[u];
            d1 += (xv - e1) * (xv - e1);
            d2 += (xv - e2) * (xv - e2);
        }
        dp1[cq][tok] = d1; dp2[cq][tok] = d2;
    }
    __syncthreads();
    if (t < 64) {
        const double d1 = dp1[0][t] + dp1[1][t] + dp1[2][t] + dp1[3][t];
        const double d2 = dp2[0][t] + dp2[1][t] + dp2[2][t] + dp2[3][t];
        const int i1 = cand1[t], i2 = cand2[t];
        const int best = (d2 < d1 || (d2 == d1 && i2 < i1)) ? i2 : i1;
        bestsm[t] = best;
        idx_f[n0 + t] = (float)best;
    }
    __syncthreads();

    // 4) qe write (coalesced along tok) + commit loss
    {
        const int row = bestsm[tok];
        const float* cr = cb + (size_t)row * CCH + cq * 64;
        float* qb = qe + ((size_t)b << 18) + hw0 + tok;
        float lsum = 0.f;
        #pragma unroll 8
        for (int u = 0; u < 64; ++u) {
            const int c = cq * 64 + u;
            const float q = cr[u];
            qb[(size_t)c << 10] = q;
            const float d = xt[c * 64 + tok] - q;
            lsum += d * d;
        }
        #pragma unroll
        for (int off = 32; off; off >>= 1) lsum += __shfl_down(lsum, off);
        if ((t & 63) == 0) wsum[t >> 6] = lsum;
    }
    __syncthreads();
    if (t == 0) {
        const float s = wsum[0] + wsum[1] + wsum[2] + wsum[3];
        atomicAdd(loss, s * (1.0f / ((float)NN * (float)CCH)));
    }
}

// ---------------------------------------------------------------------------
extern "C" void kernel_launch(void* const* d_in, const int* in_sizes, int n_in,
                              void* d_out, int out_size, void* d_ws, size_t ws_size,
                              hipStream_t stream) {
    const float* x  = (const float*)d_in[0];
    const float* cb = (const float*)d_in[1];
    float* out = (float*)d_out;
    char* ws = (char*)d_ws;

    // A (frag-major) lives in d_out's qe region (16 MiB); finalize rewrites qe.
    unsigned short* A  = (unsigned short*)out;
    unsigned short* B2 = (unsigned short*)(ws + B2_OFF);
    float* hn  = (float*)(ws + HN_OFF);
    float* pd1 = (float*)(ws + P1D_OFF);
    int*   pi1 = (int*)(ws + P1I_OFF);
    float* pd2 = (float*)(ws + P2D_OFF);
    int*   pi2 = (int*)(ws + P2I_OFF);

    split_x_kernel <<<NN / 64, 256, 0, stream>>>(x, A);
    split_cb_kernel<<<KK / 8, 256, 0, stream>>>(cb, B2, hn);
    vq_gemm_kernel <<<1024, 256, 0, stream>>>(A, B2, hn, pd1, pi1, pd2, pi2);
    hipMemsetAsync(out + LOSS_OFF, 0, sizeof(float), stream);
    finalize_kernel<<<NN / 64, 256, 0, stream>>>(x, cb, pd1, pi1, pd2, pi2,
                                                 out, out + IDX_OFF,
                                                 out + LOSS_OFF);
}